// Round 1
// baseline (335.991 us; speedup 1.0000x reference)
//
#include <hip/hip_runtime.h>

// QuantumCircuit: 16 qubits, 4 layers, batch 512.
// Key identity: the CNOT chain CNOT(0,1)..CNOT(14,15) is a GF(2)-linear basis
// permutation (prefix-XOR). We never move data for CNOTs; instead each Rot on
// logical qubit q after L chains becomes a pair-rotation on storage pairs
// {s, s^mask} with mask = col_q((P^-1)^L), role bit = parity(row_q(P^L) & s).
//
// Phase 1 (LDS, bits 0..13 local, 16384 amps = 128KB): init = product state
// (RY+layer0-Rot folded in, qubits 0..13), then 36 gates:
//   G1 q0..12, G2 q0..11, G3 q0..10   (all masks within bits 0..13)
// Phase 2 (registers, bits 11..15 local, 32-amp tiles): 14 gates:
//   G0 q14,15 ; G1 q13..15 ; G2 q12..15 ; G3 q11..15  (masks within bits 11..15)
// fused with the <Z0> reduction (sign = storage bit 0, which is frame-invariant).
// Reordering across the phase split was verified by commutation: a layer-j'
// gate on wire q pulled back to frame j has support in wires {0..q+(j'-j)},
// always disjoint from the deferred high wires.

#define NQ 16
#define NT 512
#define BATCH 512
#define NP1 36
#define NP2 14

// ---- compile-time generators (used for static_assert validation) ----
constexpr int cpar(unsigned x){ int p=0; while(x){ p^=1; x&=x-1; } return p; }
constexpr unsigned mask_of(int L, int q){
    unsigned m = 1u<<q;
    for(int i=0;i<L;++i) m = (m ^ (m<<1)) & 0xFFFFu;
    return m;
}
constexpr unsigned role_of(int L, int q){
    unsigned r = 1u<<q;
    for(int i=0;i<L;++i){
        unsigned rr = 0;
        for(int j=0;j<16;++j) rr |= ((unsigned)cpar(r>>j))<<j;
        r = rr;
    }
    return r;
}
constexpr int cctz(unsigned x){ int n=0; while(!(x&1u)){ x>>=1; ++n; } return n; }

// ---- gate tables (hard-coded; validated below) ----
// Pass 1: G1 q=0..12, G2 q=0..11, G3 q=0..10
constexpr unsigned short P1_M[NP1] = {
 0x0003,0x0006,0x000C,0x0018,0x0030,0x0060,0x00C0,0x0180,0x0300,0x0600,0x0C00,0x1800,0x3000,
 0x0005,0x000A,0x0014,0x0028,0x0050,0x00A0,0x0140,0x0280,0x0500,0x0A00,0x1400,0x2800,
 0x000F,0x001E,0x003C,0x0078,0x00F0,0x01E0,0x03C0,0x0780,0x0F00,0x1E00,0x3C00 };
constexpr unsigned short P1_R[NP1] = {
 0x0001,0x0003,0x0007,0x000F,0x001F,0x003F,0x007F,0x00FF,0x01FF,0x03FF,0x07FF,0x0FFF,0x1FFF,
 0x0001,0x0002,0x0005,0x000A,0x0015,0x002A,0x0055,0x00AA,0x0155,0x02AA,0x0555,0x0AAA,
 0x0001,0x0003,0x0006,0x000C,0x0019,0x0033,0x0066,0x00CC,0x0199,0x0333,0x0666 };
constexpr unsigned char P1_L[NP1] = {1,1,1,1,1,1,1,1,1,1,1,1,1, 2,2,2,2,2,2,2,2,2,2,2,2, 3,3,3,3,3,3,3,3,3,3,3};
constexpr unsigned char P1_Q[NP1] = {0,1,2,3,4,5,6,7,8,9,10,11,12, 0,1,2,3,4,5,6,7,8,9,10,11, 0,1,2,3,4,5,6,7,8,9,10};

// Pass 2: G0 q14,15 ; G1 q13..15 ; G2 q12..15 ; G3 q11..15 (circuit order)
constexpr unsigned short P2_M[NP2] = {0x4000,0x8000, 0x6000,0xC000,0x8000, 0x5000,0xA000,0x4000,0x8000, 0x7800,0xF000,0xE000,0xC000,0x8000};
constexpr unsigned short P2_R[NP2] = {0x4000,0x8000, 0x3FFF,0x7FFF,0xFFFF, 0x1555,0x2AAA,0x5555,0xAAAA, 0x0CCC,0x1999,0x3333,0x6666,0xCCCC};
constexpr unsigned char P2_L[NP2] = {0,0,1,1,1,2,2,2,2,3,3,3,3,3};
constexpr unsigned char P2_Q[NP2] = {14,15,13,14,15,12,13,14,15,11,12,13,14,15};

// validate tables against generators
static_assert(mask_of(1,12)==0x3000 && role_of(1,12)==0x1FFF, "p1 g1");
static_assert(mask_of(2,11)==0x2800 && role_of(2,11)==0x0AAA, "p1 g2");
static_assert(mask_of(3,10)==0x3C00 && role_of(3,10)==0x0666, "p1 g3");
static_assert(mask_of(3,4)==0x00F0 && role_of(3,4)==0x0019, "p1 g3b");
static_assert(mask_of(1,13)==0x6000 && role_of(1,13)==0x3FFF, "p2 g1");
static_assert(mask_of(2,14)==0x4000 && role_of(2,14)==0x5555, "p2 g2");
static_assert(mask_of(3,11)==0x7800 && role_of(3,11)==0x0CCC, "p2 g3a");
static_assert(mask_of(3,13)==0xE000 && role_of(3,13)==0x3333, "p2 g3b");
static_assert(role_of(4,0)==0x0001, "measure bit0 frame-invariant");

__device__ __forceinline__ float2 cmul(float2 a, float2 b){
    return make_float2(a.x*b.x - a.y*b.y, a.x*b.y + a.y*b.x);
}

// Rot(phi,theta,omega) = RZ(omega) RY(theta) RZ(phi); u = {00r,00i,01r,01i,10r,10i,11r,11i}
__device__ __forceinline__ void make_rot(const float* __restrict__ params, int L, int q, float u[8]){
    const float* pp = params + (L*NQ + q)*3;
    float phi = pp[0], th = pp[1], om = pp[2];
    float s, c;   sincosf(0.5f*th, &s, &c);
    float sap, cap; sincosf(0.5f*(phi+om), &sap, &cap);
    float sam, cam; sincosf(0.5f*(phi-om), &sam, &cam);
    u[0] =  c*cap; u[1] = -c*sap;   // e^{-i(phi+om)/2} c
    u[2] = -s*cam; u[3] = -s*sam;   // -e^{+i(phi-om)/2} s
    u[4] =  s*cam; u[5] = -s*sam;   // e^{-i(phi-om)/2} s
    u[6] =  c*cap; u[7] =  c*sap;   // e^{+i(phi+om)/2} c
}
// u <- u * RY(a)  (RY applied first in the circuit)
__device__ __forceinline__ void fuse_ry(float a, float u[8]){
    float sa, ca; sincosf(0.5f*a, &sa, &ca);
    float f0r =  u[0]*ca + u[2]*sa, f0i =  u[1]*ca + u[3]*sa;
    float f1r = -u[0]*sa + u[2]*ca, f1i = -u[1]*sa + u[3]*ca;
    float g0r =  u[4]*ca + u[6]*sa, g0i =  u[5]*ca + u[7]*sa;
    float g1r = -u[4]*sa + u[6]*ca, g1i = -u[5]*sa + u[7]*ca;
    u[0]=f0r; u[1]=f0i; u[2]=f1r; u[3]=f1i; u[4]=g0r; u[5]=g0i; u[6]=g1r; u[7]=g1i;
}

__launch_bounds__(NT, 1)
__global__ void qsim_kernel(const float* __restrict__ inputs,
                            const float* __restrict__ params,
                            float* __restrict__ out)
{
    __shared__ float2 sAmp[16384];       // 128 KB: amplitudes, storage bits 0..13
    __shared__ float  gm[NP1+NP2][8];    // gate matrices
    __shared__ float2 vq[14][2];         // init product vectors (qubits 0..13)
    __shared__ float2 hiS[32];           // partial products over bits 9..13
    __shared__ float  red[NT/64];

    const int t = threadIdx.x;           // 9 bits
    const int b = blockIdx.x;            // batch element

    // ---- Phase A: build all gate matrices + product vectors ----
    if (t < NP1 + NP2) {
        float u[8];
        int L, q;
        if (t < NP1) { L = P1_L[t]; q = P1_Q[t]; }
        else         { L = P2_L[t-NP1]; q = P2_Q[t-NP1]; }
        make_rot(params, L, q, u);
        if (t >= NP1 && L == 0) fuse_ry(inputs[b*NQ + q], u);   // G0 q=14,15: Rot*RY
        #pragma unroll
        for (int i = 0; i < 8; ++i) gm[t][i] = u[i];
    } else if (t >= 64 && t < 78) {
        int q = t - 64;                                          // qubits 0..13
        float u[8];
        make_rot(params, 0, q, u);
        fuse_ry(inputs[b*NQ + q], u);
        vq[q][0] = make_float2(u[0], u[1]);                      // col 0 of fused
        vq[q][1] = make_float2(u[4], u[5]);
    }
    __syncthreads();

    // ---- Phase B: high-bit partial products; per-thread base product ----
    if (t < 32) {
        float2 h = vq[9][t & 1];
        #pragma unroll
        for (int q = 10; q <= 13; ++q) h = cmul(h, vq[q][(t >> (q-9)) & 1]);
        hiS[t] = h;
    }
    float2 base = vq[0][t & 1];
    #pragma unroll
    for (int q = 1; q <= 8; ++q) base = cmul(base, vq[q][(t >> q) & 1]);
    __syncthreads();

    // ---- init: product state over qubits 0..13 (bits 14,15 implicitly 0) ----
    #pragma unroll 4
    for (int j = 0; j < 32; ++j) sAmp[(j << 9) | t] = cmul(base, hiS[j]);
    __syncthreads();

    // ---- Pass 1: 36 gates in LDS ----
    for (int g = 0; g < NP1; ++g) {
        const unsigned m = P1_M[g], r = P1_R[g];
        const int piv = __ffs((int)m) - 1;
        const unsigned lowm = (1u << piv) - 1u;
        const float u00r=gm[g][0], u00i=gm[g][1], u01r=gm[g][2], u01i=gm[g][3];
        const float u10r=gm[g][4], u10i=gm[g][5], u11r=gm[g][6], u11i=gm[g][7];
        #pragma unroll 4
        for (int k = 0; k < 16; ++k) {
            const unsigned p  = (unsigned)((k << 9) | t);         // pair index, 13b
            const unsigned s0 = ((p & ~lowm) << 1) | (p & lowm);  // insert 0 at piv
            const unsigned s1 = s0 ^ m;
            const bool br = (__popc(s0 & r) & 1);
            const float2 A0 = sAmp[s0], A1 = sAmp[s1];
            const float e00r = br?u11r:u00r, e00i = br?u11i:u00i;
            const float e01r = br?u10r:u01r, e01i = br?u10i:u01i;
            const float e10r = br?u01r:u10r, e10i = br?u01i:u10i;
            const float e11r = br?u00r:u11r, e11i = br?u00i:u11i;
            const float o0r = e00r*A0.x - e00i*A0.y + e01r*A1.x - e01i*A1.y;
            const float o0i = e00r*A0.y + e00i*A0.x + e01r*A1.y + e01i*A1.x;
            const float o1r = e10r*A0.x - e10i*A0.y + e11r*A1.x - e11i*A1.y;
            const float o1i = e10r*A0.y + e10i*A0.x + e11r*A1.y + e11i*A1.x;
            sAmp[s0] = make_float2(o0r, o0i);
            sAmp[s1] = make_float2(o1r, o1i);
        }
        __syncthreads();
    }

    // ---- Pass 2: 14 gates on 32-amp register tiles (bits 11..15) + measure ----
    float acc = 0.f;
    for (int kk = 0; kk < 4; ++kk) {
        const int f = t | (kk << 9);     // fixed storage bits 0..10
        float ar[32], ai[32];
        #pragma unroll
        for (int j = 0; j < 8; ++j) { float2 v = sAmp[f | (j << 11)]; ar[j] = v.x; ai[j] = v.y; }
        #pragma unroll
        for (int j = 8; j < 32; ++j) { ar[j] = 0.f; ai[j] = 0.f; }

        // G0 q14 (mask local 8): partner amps are zero -> pure scale/spread
        {
            const float u00r=gm[NP1+0][0], u00i=gm[NP1+0][1], u10r=gm[NP1+0][4], u10i=gm[NP1+0][5];
            #pragma unroll
            for (int l = 0; l < 8; ++l) {
                const float xr = ar[l], xi = ai[l];
                ar[l]   = u00r*xr - u00i*xi;  ai[l]   = u00r*xi + u00i*xr;
                ar[l+8] = u10r*xr - u10i*xi;  ai[l+8] = u10r*xi + u10i*xr;
            }
        }
        // G0 q15 (mask local 16): partner amps zero
        {
            const float u00r=gm[NP1+1][0], u00i=gm[NP1+1][1], u10r=gm[NP1+1][4], u10i=gm[NP1+1][5];
            #pragma unroll
            for (int l = 0; l < 16; ++l) {
                const float xr = ar[l], xi = ai[l];
                ar[l]    = u00r*xr - u00i*xi;  ai[l]    = u00r*xi + u00i*xr;
                ar[l+16] = u10r*xr - u10i*xi;  ai[l+16] = u10r*xi + u10i*xr;
            }
        }
        // generic gates 2..13
        #pragma unroll
        for (int g = 2; g < NP2; ++g) {
            const unsigned ml   = (unsigned)P2_M[g] >> 11;
            const unsigned rl   = ((unsigned)P2_R[g] >> 11) & 31u;
            const unsigned rfix = (unsigned)P2_R[g] & 0x7FFu;
            const int piv = cctz(ml);
            const unsigned lowm = (1u << piv) - 1u;
            const float u00r=gm[NP1+g][0], u00i=gm[NP1+g][1], u01r=gm[NP1+g][2], u01i=gm[NP1+g][3];
            const float u10r=gm[NP1+g][4], u10i=gm[NP1+g][5], u11r=gm[NP1+g][6], u11i=gm[NP1+g][7];
            const bool pf = (__popc((unsigned)f & rfix) & 1);
            // effective matrix for role-parity pf (per-pair compile-time flip below)
            const float e00r = pf?u11r:u00r, e00i = pf?u11i:u00i;
            const float e01r = pf?u10r:u01r, e01i = pf?u10i:u01i;
            const float e10r = pf?u01r:u10r, e10i = pf?u01i:u10i;
            const float e11r = pf?u00r:u11r, e11i = pf?u00i:u11i;
            #pragma unroll
            for (int k = 0; k < 16; ++k) {
                const unsigned l0 = (((unsigned)k & ~lowm) << 1) | ((unsigned)k & lowm);
                const unsigned l1 = l0 ^ ml;
                const int c = cpar(l0 & rl);   // compile-time after unroll
                const float q00r = c? e11r : e00r, q00i = c? e11i : e00i;
                const float q01r = c? e10r : e01r, q01i = c? e10i : e01i;
                const float q10r = c? e01r : e10r, q10i = c? e01i : e10i;
                const float q11r = c? e00r : e11r, q11i = c? e00i : e11i;
                const float A0r = ar[l0], A0i = ai[l0], A1r = ar[l1], A1i = ai[l1];
                ar[l0] = q00r*A0r - q00i*A0i + q01r*A1r - q01i*A1i;
                ai[l0] = q00r*A0i + q00i*A0r + q01r*A1i + q01i*A1r;
                ar[l1] = q10r*A0r - q10i*A0i + q11r*A1r - q11i*A1i;
                ai[l1] = q10r*A0i + q10i*A0r + q11r*A1i + q11i*A1r;
            }
        }
        // measure contribution: sign from storage bit 0 (= logical wire-0 bit)
        float s2 = 0.f;
        #pragma unroll
        for (int l = 0; l < 32; ++l) s2 += ar[l]*ar[l] + ai[l]*ai[l];
        acc += (f & 1) ? -s2 : s2;
    }

    // ---- reduce: wave then block ----
    #pragma unroll
    for (int off = 32; off > 0; off >>= 1) acc += __shfl_down(acc, off, 64);
    if ((t & 63) == 0) red[t >> 6] = acc;
    __syncthreads();
    if (t == 0) {
        float tot = 0.f;
        #pragma unroll
        for (int w = 0; w < NT/64; ++w) tot += red[w];
        out[b] = tot;
    }
}

extern "C" void kernel_launch(void* const* d_in, const int* in_sizes, int n_in,
                              void* d_out, int out_size, void* d_ws, size_t ws_size,
                              hipStream_t stream) {
    (void)in_sizes; (void)n_in; (void)out_size; (void)d_ws; (void)ws_size;
    const float* inputs = (const float*)d_in[0];   // (512,16) f32
    const float* params = (const float*)d_in[1];   // (4,16,3) f32
    float* out = (float*)d_out;                    // (512,) f32
    qsim_kernel<<<BATCH, NT, 0, stream>>>(inputs, params, out);
}

// Round 2
// 81.493 us; speedup vs baseline: 4.1230x; 4.1230x over previous
//
#include <hip/hip_runtime.h>

// QuantumCircuit 16q/4layers/batch512 via EXACT MPS (bond dim 16).
//
// Circuit = 4 × [Rot layer ; CNOT staircase 0->15]. The staircase maps
// |i> -> |j>, j_k = i_0^...^i_k (prefix XOR), which is an MPO of bond dim 2:
//   W_0[c'](j,s)        = d(j=s)   d(c'=j)
//   W_k[c,c'](j,s)      = d(j=s^c) d(c'=j)    (1<=k<=14)
//   W_15[c](j,s)        = d(j=s^c)
// Site-tensor evolution is LOCAL, and every chain's d(c'=j) pins the next
// Rot's input index, so the tensor after 3 chains+Rots is a closed-form
// product (no sums) for interior sites:
//   r3[aL, j, aR] = U3[j,d3] U2[d3^c3,d2] U1[d2^c2,d1] v[d1^c1]
//   (aL bits c1..c3 = left chain bonds 1..3, aR bits d1..d3 = right)
// Chain 4 then gives A[(c4*8+aL), j, (c4'*8+b)] = d(c4'=j) r3[aL, j^c4, b]:
// the right-bond high bit is pinned to the physical index, so the <Z0>
// transfer matrix stays BLOCK-DIAGONAL in that bit. Sweep recursion on the
// two 8x8 blocks Lam_c:
//   step1: T[j][c*8+a][b]  = sum_a' Lam_c[a][a'] r3[a', j^c, b]
//   step2: Lam'_j[b][b']   = sum_{c,a} conj(r3[a, j^c, b]) T[j][c*8+a][b']
// Site 0 (no left bond): B0[j][b] = U3[j,d3]U2[d3,d2]U1[d2,d1]v[d1],
//   Lam_c[b][b'] = z_c conj(B0[c,b]) B0[c,b'],  z = (+1,-1)  (Z on wire 0).
// Site 15 (no right bond): r15[a,k] = sum_s U3[k,s3]U2[s3^c3,s2]U1[s2^c2,s1]v[s1^c1]
//   M = sum_k Re( r15[.,k]^H (Lam0+Lam1) r15[.,k] ).
// Verified symbolically on identity parameters (M=1 propagates exactly).
//
// Parallelization: 1 wave (64 threads) per batch element, 512 blocks,
// ~7 KB LDS, ~70 cmul/lane/site, wave-internal sync only.

#define NQ 16

__device__ __forceinline__ float2 cmul(float2 a, float2 b){
    return make_float2(a.x*b.x - a.y*b.y, a.x*b.y + a.y*b.x);
}
__device__ __forceinline__ float2 cmulc(float2 a, float2 b){   // conj(a)*b
    return make_float2(a.x*b.x + a.y*b.y, a.x*b.y - a.y*b.x);
}

// Rot(phi,theta,omega) = RZ(omega) RY(theta) RZ(phi); u = {00r,00i,01r,01i,10r,10i,11r,11i}
__device__ __forceinline__ void make_rot(const float* __restrict__ params, int L, int q, float u[8]){
    const float* pp = params + (L*NQ + q)*3;
    float phi = pp[0], th = pp[1], om = pp[2];
    float s, c;     sincosf(0.5f*th, &s, &c);
    float sap, cap; sincosf(0.5f*(phi+om), &sap, &cap);
    float sam, cam; sincosf(0.5f*(phi-om), &sam, &cam);
    u[0] =  c*cap; u[1] = -c*sap;
    u[2] = -s*cam; u[3] = -s*sam;
    u[4] =  s*cam; u[5] = -s*sam;
    u[6] =  c*cap; u[7] =  c*sap;
}
// u <- u * RY(a)  (RY applied first in the circuit)
__device__ __forceinline__ void fuse_ry(float a, float u[8]){
    float sa, ca; sincosf(0.5f*a, &sa, &ca);
    float f0r =  u[0]*ca + u[2]*sa, f0i =  u[1]*ca + u[3]*sa;
    float f1r = -u[0]*sa + u[2]*ca, f1i = -u[1]*sa + u[3]*ca;
    float g0r =  u[4]*ca + u[6]*sa, g0i =  u[5]*ca + u[7]*sa;
    float g1r = -u[4]*sa + u[6]*ca, g1i = -u[5]*sa + u[7]*ca;
    u[0]=f0r; u[1]=f0i; u[2]=f1r; u[3]=f1i; u[4]=g0r; u[5]=g0i; u[6]=g1r; u[7]=g1i;
}

__launch_bounds__(64)
__global__ void qmps_kernel(const float* __restrict__ inputs,
                            const float* __restrict__ params,
                            float* __restrict__ out)
{
    __shared__ float2 U[3][NQ][2][2];     // U[l][q] = Rot(params[l+1, q])
    __shared__ float2 v[NQ][2];           // Rot(params[0,q])*RY(x_q)*|0>
    __shared__ float2 r3[8][2][8];        // [aL][j][aR]
    __shared__ float2 Tt[2][16][8];       // [j][c*8+a][b]
    __shared__ float2 Lam[2][2][8][8];    // [buf][c-block][row][col]
    __shared__ float2 B0[2][8];
    __shared__ float2 r15[8][2];

    const int t = threadIdx.x;            // 0..63, one wave
    const int b = blockIdx.x;             // batch element

    // ---- build gate matrices + init vectors ----
    if (t < 48) {
        int l = t >> 4, q = t & 15;       // l=0..2 -> circuit layer l+1
        float u[8]; make_rot(params, l+1, q, u);
        U[l][q][0][0] = make_float2(u[0],u[1]); U[l][q][0][1] = make_float2(u[2],u[3]);
        U[l][q][1][0] = make_float2(u[4],u[5]); U[l][q][1][1] = make_float2(u[6],u[7]);
    } else {
        int q = t - 48;
        float u[8]; make_rot(params, 0, q, u);
        fuse_ry(inputs[b*NQ + q], u);
        v[q][0] = make_float2(u[0],u[1]);       // column 0 of Rot*RY
        v[q][1] = make_float2(u[4],u[5]);
    }
    __syncthreads();

    // ---- site 0: B0[j][ap] = U3[j,d3] U2[d3,d2] U1[d2,d1] v[d1] ----
    if (t < 16) {
        int j = t >> 3, ap = t & 7;
        int d1 = ap & 1, d2 = (ap>>1)&1, d3 = (ap>>2)&1;
        B0[j][ap] = cmul(U[2][0][j][d3],
                    cmul(U[1][0][d3][d2],
                    cmul(U[0][0][d2][d1], v[0][d1])));
    }
    __syncthreads();
    // Lam init: Lam_c[b][b'] = z_c * conj(B0[c,b]) * B0[c,b']
    #pragma unroll
    for (int k = 0; k < 2; ++k) {
        int e  = t + (k << 6);
        int c  = e >> 6, bb = (e >> 3) & 7, bp = e & 7;
        float2 val = cmulc(B0[c][bb], B0[c][bp]);
        float  s   = c ? -1.f : 1.f;
        Lam[0][c][bb][bp] = make_float2(s*val.x, s*val.y);
    }
    __syncthreads();

    // ---- interior sites 1..14 ----
    int cur = 0;
    for (int site = 1; site <= 14; ++site) {
        // (a) r3[aL][j][aR] : 2 entries/lane, 3 cmul each
        #pragma unroll
        for (int k = 0; k < 2; ++k) {
            int e  = (t << 1) | k;                   // 0..127
            int aL = e >> 4, j = (e >> 3) & 1, aR = e & 7;
            int c1 = aL & 1, c2 = (aL>>1)&1, c3 = (aL>>2)&1;
            int d1 = aR & 1, d2 = (aR>>1)&1, d3 = (aR>>2)&1;
            r3[aL][j][aR] = cmul(U[2][site][j][d3],
                            cmul(U[1][site][d3^c3][d2],
                            cmul(U[0][site][d2^c2][d1], v[site][d1^c1])));
        }
        __syncthreads();
        // (b) step1: T[j][c*8+a][b] = sum_ap Lam_c[a][ap] * r3[ap][j^c][b]
        {
            int c = t >> 5, a = (t >> 2) & 7, bq = t & 3;
            #pragma unroll
            for (int j = 0; j < 2; ++j)
                #pragma unroll
                for (int h = 0; h < 2; ++h) {
                    int bb = bq + (h << 2);
                    float2 acc = make_float2(0.f, 0.f);
                    #pragma unroll
                    for (int ap = 0; ap < 8; ++ap) {
                        float2 p = cmul(Lam[cur][c][a][ap], r3[ap][j^c][bb]);
                        acc.x += p.x; acc.y += p.y;
                    }
                    Tt[j][c*8 + a][bb] = acc;
                }
        }
        __syncthreads();
        // (c) step2: Lam'_j[b][b'] = sum_{c,a} conj(r3[a][j^c][b]) * T[j][c*8+a][b']
        {
            int j = t >> 5, bb = (t >> 2) & 7, bq = t & 3;
            #pragma unroll
            for (int h = 0; h < 2; ++h) {
                int bp = bq + (h << 2);
                float2 acc = make_float2(0.f, 0.f);
                #pragma unroll
                for (int c = 0; c < 2; ++c)
                    #pragma unroll
                    for (int a = 0; a < 8; ++a) {
                        float2 p = cmulc(r3[a][j^c][bb], Tt[j][c*8 + a][bp]);
                        acc.x += p.x; acc.y += p.y;
                    }
                Lam[cur^1][j][bb][bp] = acc;
            }
        }
        __syncthreads();
        cur ^= 1;
    }

    // ---- site 15: r15[a][k] = sum_s U3[k,s3] U2[s3^c3,s2] U1[s2^c2,s1] v[s1^c1] ----
    if (t < 16) {
        int a = t >> 1, k = t & 1;
        int c1 = a & 1, c2 = (a>>1)&1, c3 = (a>>2)&1;
        float2 in1[2], in2[2];
        #pragma unroll
        for (int s2 = 0; s2 < 2; ++s2) {
            float2 acc = make_float2(0.f, 0.f);
            #pragma unroll
            for (int s1 = 0; s1 < 2; ++s1) {
                float2 p = cmul(U[0][15][s2^c2][s1], v[15][s1^c1]);
                acc.x += p.x; acc.y += p.y;
            }
            in1[s2] = acc;
        }
        #pragma unroll
        for (int s3 = 0; s3 < 2; ++s3) {
            float2 acc = make_float2(0.f, 0.f);
            #pragma unroll
            for (int s2 = 0; s2 < 2; ++s2) {
                float2 p = cmul(U[1][15][s3^c3][s2], in1[s2]);
                acc.x += p.x; acc.y += p.y;
            }
            in2[s3] = acc;
        }
        float2 acc = make_float2(0.f, 0.f);
        #pragma unroll
        for (int s3 = 0; s3 < 2; ++s3) {
            float2 p = cmul(U[2][15][k][s3], in2[s3]);
            acc.x += p.x; acc.y += p.y;
        }
        r15[a][k] = acc;
    }
    __syncthreads();

    // ---- merge: M = sum_k Re( r15[.,k]^H (Lam0+Lam1) r15[.,k] ) ----
    float m = 0.f;
    {
        int k = t >> 5, a = (t >> 2) & 7, aq = t & 3;
        #pragma unroll
        for (int h = 0; h < 2; ++h) {
            int ap = aq + (h << 2);
            float2 ls = Lam[cur][0][a][ap];
            float2 l1 = Lam[cur][1][a][ap];
            ls.x += l1.x; ls.y += l1.y;
            float2 ra = r15[a][k];               // conjugated below
            float2 t1 = cmul(ls, r15[ap][k]);
            m += ra.x*t1.x + ra.y*t1.y;          // Re(conj(ra)*t1)
        }
    }
    #pragma unroll
    for (int off = 32; off > 0; off >>= 1) m += __shfl_down(m, off, 64);
    if (t == 0) out[b] = m;
}

extern "C" void kernel_launch(void* const* d_in, const int* in_sizes, int n_in,
                              void* d_out, int out_size, void* d_ws, size_t ws_size,
                              hipStream_t stream) {
    (void)n_in; (void)out_size; (void)d_ws; (void)ws_size;
    const float* inputs = (const float*)d_in[0];   // (B,16) f32
    const float* params = (const float*)d_in[1];   // (4,16,3) f32
    float* out = (float*)d_out;                    // (B,) f32
    const int B = in_sizes[0] / NQ;
    qmps_kernel<<<B, 64, 0, stream>>>(inputs, params, out);
}